// Round 1
// baseline (11582.829 us; speedup 1.0000x reference)
//
#include <hip/hip_runtime.h>
#include <cstdint>

#define SQ 4096
#define FD 256
#define HD 512
#define GD 2048

// workspace layout (float elements)
#define WS_X       0                         // x [4096][512]
#define WS_XPROJ   (WS_X + SQ*HD)            // xproj [2][4096][2048]
#define WS_WT      (WS_XPROJ + 2*SQ*GD)      // conv_w transposed [2][256][256]
#define WS_LINT    (WS_WT + 2*FD*FD)         // lin_w transposed [256][256]
#define WS_FLAGS   (WS_LINT + FD*FD)         // 1024 ints (2 dirs x 16 blocks x 32 spacing)

__device__ __forceinline__ float sigf(float x) { return 1.f / (1.f + __expf(-x)); }

// ---------------- prep: transpose small weights, zero flags ----------------
__global__ __launch_bounds__(256) void prep_kernel(const float* __restrict__ conv_w,
                                                   const float* __restrict__ lin_w,
                                                   float* __restrict__ Wt,
                                                   float* __restrict__ linT,
                                                   int* __restrict__ flags) {
  int n = blockIdx.x * 256 + threadIdx.x;
  if (n < 1024) flags[n] = 0;
  if (n < 2 * FD * FD) {
    // Wt[k][f][o] = conv_w[o][k][f]
    int o = n & 255, f = (n >> 8) & 255, k = n >> 16;
    Wt[n] = conv_w[o * 512 + k * 256 + f];
  } else {
    int m = n - 2 * FD * FD;   // < 65536 (grid = 768 blocks)
    int o = m & 255, f = m >> 8;
    linT[m] = lin_w[o * 256 + f];   // linT[f][o] = lin_w[o][f]
  }
}

// ---------------- char CNN + concat into x ----------------
__global__ __launch_bounds__(256) void charcnn_kernel(const float* __restrict__ wemb,
    const int* __restrict__ cidx, const float* __restrict__ cemb,
    const float* __restrict__ Wt, const float* __restrict__ conv_b,
    const float* __restrict__ linT, const float* __restrict__ lin_b,
    float* __restrict__ x) {
  __shared__ float ceT[256][20];   // [f][l], padded pitch 20 (16B-aligned rows)
  __shared__ float pooled[256];
  int s = blockIdx.x, o = threadIdx.x;
  #pragma unroll
  for (int l = 0; l < 16; ++l) {
    int idx = cidx[s * 16 + l];              // uniform -> scalar load
    ceT[o][l] = cemb[idx * 256 + o];         // coalesced global read
  }
  __syncthreads();
  float acc[15];
  float cb = conv_b[o];
  #pragma unroll
  for (int l = 0; l < 15; ++l) acc[l] = cb;
  for (int f = 0; f < 256; ++f) {
    float w0 = Wt[f * 256 + o];              // k=0, coalesced
    float w1 = Wt[65536 + f * 256 + o];      // k=1
    float4 ca = *(const float4*)&ceT[f][0];  // broadcast LDS reads
    float4 cv = *(const float4*)&ceT[f][4];
    float4 cc = *(const float4*)&ceT[f][8];
    float4 cd = *(const float4*)&ceT[f][12];
    float c[16] = {ca.x, ca.y, ca.z, ca.w, cv.x, cv.y, cv.z, cv.w,
                   cc.x, cc.y, cc.z, cc.w, cd.x, cd.y, cd.z, cd.w};
    #pragma unroll
    for (int l = 0; l < 15; ++l) acc[l] += c[l] * w0 + c[l + 1] * w1;
  }
  float m = 0.f;   // relu then max == max(0, max)
  #pragma unroll
  for (int l = 0; l < 15; ++l) m = fmaxf(m, acc[l]);
  pooled[o] = m;
  __syncthreads();
  float a2 = lin_b[o];
  for (int f = 0; f < 256; f += 4) {
    float4 p = *(const float4*)&pooled[f];
    a2 += p.x * linT[(f + 0) * 256 + o] + p.y * linT[(f + 1) * 256 + o]
        + p.z * linT[(f + 2) * 256 + o] + p.w * linT[(f + 3) * 256 + o];
  }
  x[(size_t)s * 512 + o] = wemb[(size_t)s * 256 + o];
  x[(size_t)s * 512 + 256 + o] = a2;
}

// ---------------- input projection GEMM: xproj[dir][t][g] = x[t].Wih_dir^T + bias ----------------
__global__ __launch_bounds__(256) void xproj_kernel(const float* __restrict__ x,
    const float* __restrict__ Wih_f, const float* __restrict__ Wih_r,
    const float* __restrict__ bih_f, const float* __restrict__ bhh_f,
    const float* __restrict__ bih_r, const float* __restrict__ bhh_r,
    float* __restrict__ xproj) {
  __shared__ float As[64][33];
  __shared__ float Bs[64][33];
  int dir = blockIdx.z;
  const float* B  = dir ? Wih_r : Wih_f;
  const float* b1 = dir ? bih_r : bih_f;
  const float* b2 = dir ? bhh_r : bhh_f;
  int m0 = blockIdx.x * 64, n0 = blockIdx.y * 64;
  int tid = threadIdx.x, tx = tid & 15, ty = tid >> 4;
  float acc[4][4];
  #pragma unroll
  for (int j = 0; j < 4; ++j) {
    float bias = b1[n0 + tx * 4 + j] + b2[n0 + tx * 4 + j];
    #pragma unroll
    for (int i = 0; i < 4; ++i) acc[i][j] = bias;
  }
  int lc = tid & 31, lr0 = tid >> 5;
  for (int k0 = 0; k0 < 512; k0 += 32) {
    #pragma unroll
    for (int i = 0; i < 8; ++i) {
      As[lr0 + 8 * i][lc] = x[(size_t)(m0 + lr0 + 8 * i) * 512 + k0 + lc];
      Bs[lr0 + 8 * i][lc] = B[(size_t)(n0 + lr0 + 8 * i) * 512 + k0 + lc];
    }
    __syncthreads();
    #pragma unroll
    for (int kk = 0; kk < 32; ++kk) {
      float a0 = As[ty * 4 + 0][kk], a1 = As[ty * 4 + 1][kk];
      float a2 = As[ty * 4 + 2][kk], a3 = As[ty * 4 + 3][kk];
      float q0 = Bs[tx * 4 + 0][kk], q1 = Bs[tx * 4 + 1][kk];
      float q2 = Bs[tx * 4 + 2][kk], q3 = Bs[tx * 4 + 3][kk];
      acc[0][0] += a0 * q0; acc[0][1] += a0 * q1; acc[0][2] += a0 * q2; acc[0][3] += a0 * q3;
      acc[1][0] += a1 * q0; acc[1][1] += a1 * q1; acc[1][2] += a1 * q2; acc[1][3] += a1 * q3;
      acc[2][0] += a2 * q0; acc[2][1] += a2 * q1; acc[2][2] += a2 * q2; acc[2][3] += a2 * q3;
      acc[3][0] += a3 * q0; acc[3][1] += a3 * q1; acc[3][2] += a3 * q2; acc[3][3] += a3 * q3;
    }
    __syncthreads();
  }
  size_t base = (size_t)dir * SQ * GD;
  #pragma unroll
  for (int i = 0; i < 4; ++i) {
    float4 v = make_float4(acc[i][0], acc[i][1], acc[i][2], acc[i][3]);
    *(float4*)&xproj[base + (size_t)(m0 + ty * 4 + i) * GD + n0 + tx * 4] = v;
  }
}

// ---------------- persistent bidirectional LSTM recurrence ----------------
// 32 blocks: blocks 0..15 forward, 16..31 reverse. Each block owns 32 h-indices
// (=128 Whh rows), weights register-resident (128 f32 VGPR/thread).
// Cross-block publish: relaxed agent-scope atomics + s_waitcnt vmcnt(0) + flag=t+1.
__global__ __launch_bounds__(512, 2) void lstm_kernel(const float* __restrict__ xproj,
    const float* __restrict__ Whh_f, const float* __restrict__ Whh_r,
    int* flags, float* out) {
  __shared__ float h4[4 * 132];   // h split in 4 chunks of 128, pitch 132 (bank-spread)
  __shared__ float g_lds[128];
  __shared__ float c_s[32];
  int dir = blockIdx.x >> 4;
  int blk = blockIdx.x & 15;
  int hbase = blk * 32;
  int tid = threadIdx.x;
  const float* Whh = dir ? Whh_r : Whh_f;
  const float* xp = xproj + (size_t)dir * SQ * GD;
  int* flg = flags + dir * 512;
  int r = tid >> 2, kq = tid & 3;                       // row 0..127, K-quarter 0..3
  int Rrow = ((r >> 5) << 9) + hbase + (r & 31);        // gate*512 + hbase + hoff

  float wreg[128];
  {
    const float* wsrc = Whh + (size_t)Rrow * 512 + kq * 128;
    #pragma unroll
    for (int j4 = 0; j4 < 32; ++j4) {
      float4 v = *(const float4*)(wsrc + 4 * j4);
      wreg[4 * j4 + 0] = v.x; wreg[4 * j4 + 1] = v.y;
      wreg[4 * j4 + 2] = v.z; wreg[4 * j4 + 3] = v.w;
    }
  }
  if (tid < 32) c_s[tid] = 0.f;

  for (int t = 0; t < SQ; ++t) {
    int p = dir ? (SQ - 1 - t) : t;
    float xval = 0.f;
    if (kq == 0) xval = xp[(size_t)p * GD + Rrow];      // prefetch before poll
    if (t > 0) {
      if (tid < 64) {                                   // wave 0 polls 16 flags
        for (;;) {
          int v = (tid < 16)
            ? __hip_atomic_load(&flg[tid * 32], __ATOMIC_RELAXED, __HIP_MEMORY_SCOPE_AGENT)
            : 0x7FFFFFFF;
          if (__all(v >= t)) break;
          __builtin_amdgcn_s_sleep(2);
        }
      }
      __syncthreads();                                  // (A)
      int pprev = dir ? (p + 1) : (t - 1);
      float hv = __hip_atomic_load(&out[(size_t)pprev * 1024 + dir * 512 + tid],
                                   __ATOMIC_RELAXED, __HIP_MEMORY_SCOPE_AGENT);
      h4[(tid >> 7) * 132 + (tid & 127)] = hv;
    } else {
      h4[(tid >> 7) * 132 + (tid & 127)] = 0.f;
    }
    __syncthreads();                                    // (B) h ready
    float acc = 0.f;
    const float* hq = &h4[kq * 132];
    #pragma unroll
    for (int j4 = 0; j4 < 32; ++j4) {
      float4 hh = *(const float4*)(hq + 4 * j4);
      acc += wreg[4 * j4 + 0] * hh.x + wreg[4 * j4 + 1] * hh.y
           + wreg[4 * j4 + 2] * hh.z + wreg[4 * j4 + 3] * hh.w;
    }
    acc += __shfl_xor(acc, 1);
    acc += __shfl_xor(acc, 2);
    if (kq == 0) g_lds[r] = acc + xval;
    __syncthreads();                                    // (C) g ready
    if (tid < 32) {                                     // gates in wave 0
      float ig = g_lds[tid], fg = g_lds[32 + tid], gg = g_lds[64 + tid], og = g_lds[96 + tid];
      float c = sigf(fg) * c_s[tid] + sigf(ig) * tanhf(gg);
      float h = sigf(og) * tanhf(c);
      c_s[tid] = c;
      __hip_atomic_store(&out[(size_t)p * 1024 + dir * 512 + hbase + tid], h,
                         __ATOMIC_RELAXED, __HIP_MEMORY_SCOPE_AGENT);
    }
    asm volatile("s_waitcnt vmcnt(0)" ::: "memory");    // h stores complete before flag
    if (tid == 0)
      __hip_atomic_store(&flg[blk * 32], t + 1, __ATOMIC_RELAXED, __HIP_MEMORY_SCOPE_AGENT);
    // LDS reuse is guarded by next iteration's (A) barrier.
  }
  if (tid < 32) {
    size_t OH = (size_t)SQ * 1024;
    int plast = dir ? 0 : (SQ - 1);
    float hlast = __hip_atomic_load(&out[(size_t)plast * 1024 + dir * 512 + hbase + tid],
                                    __ATOMIC_RELAXED, __HIP_MEMORY_SCOPE_AGENT);
    out[OH + dir * 512 + hbase + tid] = hlast;          // hidden
    out[OH + 1024 + dir * 512 + hbase + tid] = c_s[tid]; // cell
  }
}

extern "C" void kernel_launch(void* const* d_in, const int* in_sizes, int n_in,
                              void* d_out, int out_size, void* d_ws, size_t ws_size,
                              hipStream_t stream) {
  const float* wemb   = (const float*)d_in[0];
  const int*   cidx   = (const int*)d_in[1];
  const float* cemb   = (const float*)d_in[2];
  const float* conv_w = (const float*)d_in[3];
  const float* conv_b = (const float*)d_in[4];
  const float* lin_w  = (const float*)d_in[5];
  const float* lin_b  = (const float*)d_in[6];
  const float* Wih_f  = (const float*)d_in[7];
  const float* Whh_f  = (const float*)d_in[8];
  const float* bih_f  = (const float*)d_in[9];
  const float* bhh_f  = (const float*)d_in[10];
  const float* Wih_r  = (const float*)d_in[11];
  const float* Whh_r  = (const float*)d_in[12];
  const float* bih_r  = (const float*)d_in[13];
  const float* bhh_r  = (const float*)d_in[14];
  float* out = (float*)d_out;
  float* ws = (float*)d_ws;
  float* x     = ws + WS_X;
  float* xproj = ws + WS_XPROJ;
  float* Wt    = ws + WS_WT;
  float* linT  = ws + WS_LINT;
  int*   flags = (int*)(ws + WS_FLAGS);

  prep_kernel<<<768, 256, 0, stream>>>(conv_w, lin_w, Wt, linT, flags);
  charcnn_kernel<<<SQ, 256, 0, stream>>>(wemb, cidx, cemb, Wt, conv_b, linT, lin_b, x);
  xproj_kernel<<<dim3(64, 32, 2), 256, 0, stream>>>(x, Wih_f, Wih_r, bih_f, bhh_f, bih_r, bhh_r, xproj);
  lstm_kernel<<<32, 512, 0, stream>>>(xproj, Whh_f, Whh_r, flags, out);
}

// Round 4
// 8594.176 us; speedup vs baseline: 1.3478x; 1.3478x over previous
//
#include <hip/hip_runtime.h>
#include <cstdint>

#define SQ 4096
#define FD 256
#define HD 512
#define GD 2048

// workspace layout (float elements)
#define WS_X       0                         // x [4096][512]
#define WS_XPROJ   (WS_X + SQ*HD)            // xproj [2][4096][2048]
#define WS_WT      (WS_XPROJ + 2*SQ*GD)      // conv_w transposed [2][256][256]
#define WS_LINT    (WS_WT + 2*FD*FD)         // lin_w transposed [256][256]
#define WS_SYNC    (WS_LINT + FD*FD)         // payload: u64[2][2][16][16][2] = 16 KB

typedef __attribute__((ext_vector_type(4))) float f32x4;
typedef unsigned long long u64;

__device__ __forceinline__ float sigf(float x) { return 1.f / (1.f + __expf(-x)); }

#define REP32(M) M(0)M(1)M(2)M(3)M(4)M(5)M(6)M(7)M(8)M(9)M(10)M(11)M(12)M(13)M(14)M(15) \
                 M(16)M(17)M(18)M(19)M(20)M(21)M(22)M(23)M(24)M(25)M(26)M(27)M(28)M(29)M(30)M(31)

// ---------------- prep: transpose small weights, zero sync payload ----------------
__global__ __launch_bounds__(256) void prep_kernel(const float* __restrict__ conv_w,
                                                   const float* __restrict__ lin_w,
                                                   float* __restrict__ Wt,
                                                   float* __restrict__ linT,
                                                   float* __restrict__ sync) {
  int n = blockIdx.x * 256 + threadIdx.x;
  if (n < 4096) sync[n] = 0.f;               // 16 KB payload (tags := 0)
  if (n < 2 * FD * FD) {
    int o = n & 255, f = (n >> 8) & 255, k = n >> 16;
    Wt[n] = conv_w[o * 512 + k * 256 + f];   // Wt[k][f][o]
  } else {
    int m = n - 2 * FD * FD;
    int o = m & 255, f = m >> 8;
    linT[m] = lin_w[o * 256 + f];            // linT[f][o]
  }
}

// ---------------- char CNN + concat into x ----------------
__global__ __launch_bounds__(256) void charcnn_kernel(const float* __restrict__ wemb,
    const int* __restrict__ cidx, const float* __restrict__ cemb,
    const float* __restrict__ Wt, const float* __restrict__ conv_b,
    const float* __restrict__ linT, const float* __restrict__ lin_b,
    float* __restrict__ x) {
  __shared__ float ceT[256][20];
  __shared__ float pooled[256];
  int s = blockIdx.x, o = threadIdx.x;
  #pragma unroll
  for (int l = 0; l < 16; ++l) {
    int idx = cidx[s * 16 + l];
    ceT[o][l] = cemb[idx * 256 + o];
  }
  __syncthreads();
  float acc[15];
  float cb = conv_b[o];
  #pragma unroll
  for (int l = 0; l < 15; ++l) acc[l] = cb;
  for (int f = 0; f < 256; ++f) {
    float w0 = Wt[f * 256 + o];
    float w1 = Wt[65536 + f * 256 + o];
    float4 ca = *(const float4*)&ceT[f][0];
    float4 cv = *(const float4*)&ceT[f][4];
    float4 cc = *(const float4*)&ceT[f][8];
    float4 cd = *(const float4*)&ceT[f][12];
    float c[16] = {ca.x, ca.y, ca.z, ca.w, cv.x, cv.y, cv.z, cv.w,
                   cc.x, cc.y, cc.z, cc.w, cd.x, cd.y, cd.z, cd.w};
    #pragma unroll
    for (int l = 0; l < 15; ++l) acc[l] += c[l] * w0 + c[l + 1] * w1;
  }
  float m = 0.f;
  #pragma unroll
  for (int l = 0; l < 15; ++l) m = fmaxf(m, acc[l]);
  pooled[o] = m;
  __syncthreads();
  float a2 = lin_b[o];
  for (int f = 0; f < 256; f += 4) {
    float4 p = *(const float4*)&pooled[f];
    a2 += p.x * linT[(f + 0) * 256 + o] + p.y * linT[(f + 1) * 256 + o]
        + p.z * linT[(f + 2) * 256 + o] + p.w * linT[(f + 3) * 256 + o];
  }
  x[(size_t)s * 512 + o] = wemb[(size_t)s * 256 + o];
  x[(size_t)s * 512 + 256 + o] = a2;
}

// ---------------- input projection GEMM ----------------
__global__ __launch_bounds__(256) void xproj_kernel(const float* __restrict__ x,
    const float* __restrict__ Wih_f, const float* __restrict__ Wih_r,
    const float* __restrict__ bih_f, const float* __restrict__ bhh_f,
    const float* __restrict__ bih_r, const float* __restrict__ bhh_r,
    float* __restrict__ xproj) {
  __shared__ float As[64][33];
  __shared__ float Bs[64][33];
  int dir = blockIdx.z;
  const float* B  = dir ? Wih_r : Wih_f;
  const float* b1 = dir ? bih_r : bih_f;
  const float* b2 = dir ? bhh_r : bhh_f;
  int m0 = blockIdx.x * 64, n0 = blockIdx.y * 64;
  int tid = threadIdx.x, tx = tid & 15, ty = tid >> 4;
  float acc[4][4];
  #pragma unroll
  for (int j = 0; j < 4; ++j) {
    float bias = b1[n0 + tx * 4 + j] + b2[n0 + tx * 4 + j];
    #pragma unroll
    for (int i = 0; i < 4; ++i) acc[i][j] = bias;
  }
  int lc = tid & 31, lr0 = tid >> 5;
  for (int k0 = 0; k0 < 512; k0 += 32) {
    #pragma unroll
    for (int i = 0; i < 8; ++i) {
      As[lr0 + 8 * i][lc] = x[(size_t)(m0 + lr0 + 8 * i) * 512 + k0 + lc];
      Bs[lr0 + 8 * i][lc] = B[(size_t)(n0 + lr0 + 8 * i) * 512 + k0 + lc];
    }
    __syncthreads();
    #pragma unroll
    for (int kk = 0; kk < 32; ++kk) {
      float a0 = As[ty * 4 + 0][kk], a1 = As[ty * 4 + 1][kk];
      float a2 = As[ty * 4 + 2][kk], a3 = As[ty * 4 + 3][kk];
      float q0 = Bs[tx * 4 + 0][kk], q1 = Bs[tx * 4 + 1][kk];
      float q2 = Bs[tx * 4 + 2][kk], q3 = Bs[tx * 4 + 3][kk];
      acc[0][0] += a0 * q0; acc[0][1] += a0 * q1; acc[0][2] += a0 * q2; acc[0][3] += a0 * q3;
      acc[1][0] += a1 * q0; acc[1][1] += a1 * q1; acc[1][2] += a1 * q2; acc[1][3] += a1 * q3;
      acc[2][0] += a2 * q0; acc[2][1] += a2 * q1; acc[2][2] += a2 * q2; acc[2][3] += a2 * q3;
      acc[3][0] += a3 * q0; acc[3][1] += a3 * q1; acc[3][2] += a3 * q2; acc[3][3] += a3 * q3;
    }
    __syncthreads();
  }
  size_t base = (size_t)dir * SQ * GD;
  #pragma unroll
  for (int i = 0; i < 4; ++i) {
    float4 v = make_float4(acc[i][0], acc[i][1], acc[i][2], acc[i][3]);
    *(float4*)&xproj[base + (size_t)(m0 + ty * 4 + i) * GD + n0 + tx * 4] = v;
  }
}

// ---------------- persistent bidirectional LSTM recurrence ----------------
// 32 blocks: 0..15 fwd, 16..31 rev; each owns 32 h (128 Whh rows), weights in
// named f32x4 registers. h exchange: per 16B chunk two u64 words
// lo=(h0<<32)|tag, hi=(tag<<32)|h1 -- tag embedded in BOTH atomically-loaded
// words, so readers poll the data itself (single round trip, no tearing).
// Publish: lane 2j stores lo with its own hval, lane 2j+1 stores hi with its
// own hval -- all lanes use only their own registers (no shfl under
// divergence; that was round 3's bug). Double-buffered slots, exact tag match.
__global__ __launch_bounds__(512, 2) void lstm_kernel(const float* __restrict__ xproj,
    const float* __restrict__ Whh_f, const float* __restrict__ Whh_r,
    u64* __restrict__ payu, float* __restrict__ out) {
  __shared__ float h4[4 * 132];   // h chunked by K-quarter, pitch 132
  __shared__ float g_lds[128];
  int dir = blockIdx.x >> 4;
  int wid = blockIdx.x & 15;
  int hbase = wid * 32;
  int tid = threadIdx.x;

  int r = tid >> 2, kq = tid & 3;                 // row 0..127, K-quarter
  int Rrow = ((r >> 5) << 9) + hbase + (r & 31);  // gate*512 + hbase + hoff
  const float* Whh = dir ? Whh_r : Whh_f;
  const float* xp = xproj + (size_t)dir * SQ * GD;
  const f32x4* wsrc4 = (const f32x4*)(Whh + (size_t)Rrow * 512 + kq * 128);
#define LDW(i) f32x4 w##i = wsrc4[i];
  REP32(LDW)
#undef LDW

  int ib = tid >> 4, ic = tid & 15;               // reader: writer-block, chunk
  float cst = 0.f, hlast = 0.f;

  for (int t = 0; t < SQ; ++t) {
    int p = dir ? (SQ - 1 - t) : t;
    float xval = 0.f;
    if (kq == 0) xval = xp[(size_t)p * GD + Rrow];   // prefetch before poll
    if (tid < 256) {
      float v0, v1;
      if (t == 0) { v0 = 0.f; v1 = 0.f; }
      else {
        const u64* src = payu + ((((size_t)dir * 2 + ((t - 1) & 1)) * 16 + ib) * 16 + ic) * 2;
        unsigned tg = (unsigned)t;
        for (;;) {
          u64 lo = __hip_atomic_load(src,     __ATOMIC_RELAXED, __HIP_MEMORY_SCOPE_AGENT);
          u64 hi = __hip_atomic_load(src + 1, __ATOMIC_RELAXED, __HIP_MEMORY_SCOPE_AGENT);
          if ((unsigned)lo == tg && (unsigned)(hi >> 32) == tg) {
            v0 = __uint_as_float((unsigned)(lo >> 32));
            v1 = __uint_as_float((unsigned)hi);
            break;
          }
          __builtin_amdgcn_s_sleep(1);
        }
      }
      int ih = ib * 32 + ic * 2;
      h4[(ih >> 7) * 132 + (ih & 127)] = v0;
      int ih1 = ih + 1;
      h4[(ih1 >> 7) * 132 + (ih1 & 127)] = v1;
    }
    __syncthreads();                               // h ready
    float a0 = 0.f, a1 = 0.f, a2 = 0.f, a3 = 0.f;
    const f32x4* hq4 = (const f32x4*)&h4[kq * 132];
#define GST(i) { f32x4 hh = hq4[i]; \
    a0 = fmaf(w##i[0], hh[0], a0); a1 = fmaf(w##i[1], hh[1], a1); \
    a2 = fmaf(w##i[2], hh[2], a2); a3 = fmaf(w##i[3], hh[3], a3); }
    REP32(GST)
#undef GST
    float acc = (a0 + a1) + (a2 + a3);
    acc += __shfl_xor(acc, 1);
    acc += __shfl_xor(acc, 2);
    if (kq == 0) g_lds[r] = acc + xval;
    __syncthreads();                               // g ready
    if (tid < 32) {
      float ig = g_lds[tid], fg = g_lds[32 + tid], gg = g_lds[64 + tid], og = g_lds[96 + tid];
      float c = sigf(fg) * cst + sigf(ig) * tanhf(gg);
      float hval = sigf(og) * tanhf(c);
      cst = c; hlast = hval;
      out[(size_t)p * 1024 + dir * 512 + hbase + tid] = hval;
      // publish: each lane stores ONE u64 built from its OWN hval.
      // chunk j = tid>>1: lo (lane even) = (h<<32)|tag, hi (lane odd) = (tag<<32)|h
      unsigned tg = (unsigned)(t + 1);
      u64 word = (tid & 1) ? (((u64)tg << 32) | __float_as_uint(hval))
                           : (((u64)__float_as_uint(hval) << 32) | tg);
      u64* dst = payu + ((((size_t)dir * 2 + (t & 1)) * 16 + wid) * 16 + (tid >> 1)) * 2 + (tid & 1);
      __hip_atomic_store(dst, word, __ATOMIC_RELAXED, __HIP_MEMORY_SCOPE_AGENT);
    }
    // next iteration's h-ready barrier guards LDS reuse
  }
  if (tid < 32) {
    size_t OH = (size_t)SQ * 1024;
    out[OH + dir * 512 + hbase + tid] = hlast;           // hidden
    out[OH + 1024 + dir * 512 + hbase + tid] = cst;      // cell
  }
}

extern "C" void kernel_launch(void* const* d_in, const int* in_sizes, int n_in,
                              void* d_out, int out_size, void* d_ws, size_t ws_size,
                              hipStream_t stream) {
  const float* wemb   = (const float*)d_in[0];
  const int*   cidx   = (const int*)d_in[1];
  const float* cemb   = (const float*)d_in[2];
  const float* conv_w = (const float*)d_in[3];
  const float* conv_b = (const float*)d_in[4];
  const float* lin_w  = (const float*)d_in[5];
  const float* lin_b  = (const float*)d_in[6];
  const float* Wih_f  = (const float*)d_in[7];
  const float* Whh_f  = (const float*)d_in[8];
  const float* bih_f  = (const float*)d_in[9];
  const float* bhh_f  = (const float*)d_in[10];
  const float* Wih_r  = (const float*)d_in[11];
  const float* Whh_r  = (const float*)d_in[12];
  const float* bih_r  = (const float*)d_in[13];
  const float* bhh_r  = (const float*)d_in[14];
  float* out = (float*)d_out;
  float* ws = (float*)d_ws;
  float* x     = ws + WS_X;
  float* xproj = ws + WS_XPROJ;
  float* Wt    = ws + WS_WT;
  float* linT  = ws + WS_LINT;
  float* sync  = ws + WS_SYNC;

  prep_kernel<<<768, 256, 0, stream>>>(conv_w, lin_w, Wt, linT, sync);
  charcnn_kernel<<<SQ, 256, 0, stream>>>(wemb, cidx, cemb, Wt, conv_b, linT, lin_b, x);
  xproj_kernel<<<dim3(64, 32, 2), 256, 0, stream>>>(x, Wih_f, Wih_r, bih_f, bhh_f, bih_r, bhh_r, xproj);
  lstm_kernel<<<32, 512, 0, stream>>>(xproj, Whh_f, Whh_r, (u64*)sync, out);
}